// Round 4
// baseline (1351.135 us; speedup 1.0000x reference)
//
#include <hip/hip_runtime.h>
#include <hip/hip_bf16.h>

#define HWSZ (192*192)

typedef __attribute__((ext_vector_type(8))) short short8v;
typedef __attribute__((ext_vector_type(4))) float f32x4;

// ws element counts for prep'd weights
#define WG_N 331776   // conv w: [tap][oc][c]           9*192*192
#define WQ_N 110592   // qkv  w: [h][144][192]          4*144*192
#define PW_N 49152    // proj w: [h][192][64] (d pad 64) 4*192*64
#define W1_N 73728    // glu  w: [384][192] straight cast

// ---------------------------------------------------------------------------
// prep: cast/reorder all weights to bf16 layouts used by the MFMA kernels
// ---------------------------------------------------------------------------
__global__ __launch_bounds__(256)
void prep_weights(const float* __restrict__ w2_w, const float* __restrict__ qkv_w,
                  const float* __restrict__ proj_w, const float* __restrict__ w1_w,
                  __hip_bfloat16* __restrict__ wg, __hip_bfloat16* __restrict__ wq,
                  __hip_bfloat16* __restrict__ pw, __hip_bfloat16* __restrict__ w1b)
{
    int i = blockIdx.x*256 + threadIdx.x;
    if (i < WG_N) {
        int tap = i / 36864; int r = i - tap*36864;
        int oc = r / 192;    int c = r - oc*192;
        wg[i] = __float2bfloat16(w2_w[((size_t)oc*192 + c)*9 + tap]);
    } else if (i < WG_N + WQ_N) {
        int j2 = i - WG_N;
        int h = j2 / 27648; int r = j2 - h*27648;
        int j = r / 192;    int c = r - j*192;
        int row = (j<48) ? h*48+j : (j<96) ? 192+h*48+(j-48) : 384+h*48+(j-96);
        wq[j2] = __float2bfloat16(qkv_w[(size_t)row*192 + c]);
    } else if (i < WG_N + WQ_N + PW_N) {
        int j2 = i - WG_N - WQ_N;
        int h = j2 / 12288; int r = j2 - h*12288;
        int oc = r / 64;    int dd = r - oc*64;
        pw[j2] = (dd < 48) ? __float2bfloat16(proj_w[(size_t)oc*192 + h*48 + dd])
                           : __float2bfloat16(0.f);
    } else if (i < WG_N + WQ_N + PW_N + W1_N) {
        int j2 = i - WG_N - WQ_N - PW_N;
        w1b[j2] = __float2bfloat16(w1_w[j2]);
    }
}

// ---------------------------------------------------------------------------
// K0: x (fp32, NCHW) -> xbf (bf16, pixel-major [img][y][x][c])
// ---------------------------------------------------------------------------
__global__ __launch_bounds__(256)
void to_bf16_pm(const float* __restrict__ x, __hip_bfloat16* __restrict__ xbf)
{
    __shared__ __align__(16) __hip_bfloat16 sb[64][200];
    const int tid  = threadIdx.x;
    const int bimg = blockIdx.x / 576;
    const int rem  = blockIdx.x - bimg*576;
    const int y    = rem / 3;
    const int x0   = (rem - y*3) * 64;

    const float* xb = x + (size_t)bimg*192*HWSZ + (size_t)y*192 + x0;
    for (int idx = tid; idx < 192*64; idx += 256){
        int c = idx >> 6, t = idx & 63;
        sb[t][c] = __float2bfloat16(xb[(size_t)c*HWSZ + t]);
    }
    __syncthreads();
    __hip_bfloat16* gb = xbf + ((size_t)bimg*HWSZ + (size_t)y*192 + x0)*192;
    for (int idx = tid; idx < 1536; idx += 256){
        int p = idx / 24, j0 = (idx - p*24)*8;
        *(uint4*)&gb[(size_t)p*192 + j0] = *(const uint4*)&sb[p][j0];
    }
}

// ---------------------------------------------------------------------------
// K1: window attention, wave-per-window, barrier-free head loop.
// 4 waves/block, each wave = 1 window (64 tokens), all 4 heads + proj + resid.
// Per-wave LDS slice (bf16, stride 72 rows = 16B-aligned, 2-way banks):
//   q[64][72] | k[64][72] | v[48][72];  p overlays q, o overlays k.
// Fragment convention (HW-verified R2/R3):
//   A/B-frag: lane&15 = non-K index, k=(lane>>4)*8+0..7 contiguous in memory
//   D: row=(lane>>4)*4+r, col=lane&15
// ---------------------------------------------------------------------------
#define SLICE 12672   // 4608 + 4608 + 3456 bf16 elements per wave

__global__ __launch_bounds__(256, 1)
void attn_wave(const __hip_bfloat16* __restrict__ xbf,
               const float* __restrict__ x,
               const __hip_bfloat16* __restrict__ wq,
               const float* __restrict__ qkv_b,
               const __hip_bfloat16* __restrict__ pw,
               const float* __restrict__ proj_b,
               const float* __restrict__ bias_tab,
               float* __restrict__ out)
{
    __shared__ __align__(16) __hip_bfloat16 slab[4*SLICE];
    __shared__ float bias_full[64][65];

    const int tid = threadIdx.x;
    for (int i = tid; i < 4096; i += 256) {
        int tq = i >> 6, tk = i & 63;
        int dy = (tq>>3) - (tk>>3) + 7;
        int dx = (tq&7)  - (tk&7)  + 7;
        bias_full[tq][tk] = bias_tab[dy*15 + dx];
    }
    __syncthreads();   // only barrier in the kernel

    const int lane = tid & 63;
    const int wv   = tid >> 6;
    const int lx   = lane & 15;
    const int kg   = lane >> 4;

    // XCD-contiguous swizzle (1152 = 8 * 144, bijective)
    const int swz = (blockIdx.x & 7)*144 + (blockIdx.x >> 3);
    const int wid = swz*4 + wv;
    const int b   = wid / 576;
    const int wr  = wid - b*576;
    const int wi  = wr / 24;
    const int wj  = wr - wi*24;

    __hip_bfloat16* q_s = slab + wv*SLICE;   // [64][72]; p overlays
    __hip_bfloat16* k_s = q_s + 4608;        // [64][72]; o overlays
    __hip_bfloat16* v_s = k_s + 4608;        // [48][72]

    const __hip_bfloat16* xw =
        xbf + ((size_t)b*HWSZ + (size_t)(wi*8)*192 + wj*8)*192;

    // per-lane pixel offsets (elements) for tokens t = n*16+lx
    int pixoff[4];
    #pragma unroll
    for (int n=0;n<4;n++){
        int t = n*16 + lx;
        pixoff[n] = ((t>>3)*192 + (t&7))*192;
    }

    f32x4 pacc[12][4];
    #pragma unroll
    for (int m=0;m<12;m++)
        #pragma unroll
        for (int n=0;n<4;n++) pacc[m][n] = (f32x4){0.f,0.f,0.f,0.f};

    const float scale = 0.14433756729740643f; // 1/sqrt(48)
    const ushort4 zz = make_ushort4(0,0,0,0);

    #pragma unroll 1
    for (int h=0; h<4; ++h) {
        // zero q/k K-pad (cols 48..63) — overwritten by p/o of previous head
        #pragma unroll
        for (int n=0;n<4;n++){
            const int t = n*16 + lx;
            *(ushort4*)&q_s[t*72 + 48 + kg*4] = zz;
            *(ushort4*)&k_s[t*72 + 48 + kg*4] = zz;
        }

        // ---------- QKV: 9 m-tiles in 3 chunks; D[j][t] ----------
        #pragma unroll 1
        for (int mc3=0; mc3<3; ++mc3) {
            f32x4 qa[3][4];
            #pragma unroll
            for (int m=0;m<3;m++)
                #pragma unroll
                for (int n=0;n<4;n++) qa[m][n] = (f32x4){0.f,0.f,0.f,0.f};

            #pragma unroll
            for (int kc=0; kc<6; ++kc) {
                short8v bf[4];
                #pragma unroll
                for (int n=0;n<4;n++)
                    bf[n] = *(const short8v*)&xw[(size_t)pixoff[n] + kc*32 + kg*8];
                #pragma unroll
                for (int mm=0; mm<3; ++mm) {
                    const int mt = mc3*3 + mm;
                    short8v af = *(const short8v*)
                        &wq[((size_t)(h*144 + mt*16 + lx))*192 + kc*32 + kg*8];
                    #pragma unroll
                    for (int n=0;n<4;n++)
                        qa[mm][n] = __builtin_amdgcn_mfma_f32_16x16x32_bf16(
                                        af, bf[n], qa[mm][n], 0,0,0);
                }
            }
            // bias + pack + write to q/k/v slice
            #pragma unroll
            for (int mm=0; mm<3; ++mm) {
                const int mt = mc3*3 + mm;
                const int j0 = mt*16 + kg*4;
                float b4[4];
                #pragma unroll
                for (int r=0;r<4;r++){
                    int j = j0 + r;
                    int row = (j<48) ? h*48+j : (j<96) ? 192+h*48+(j-48)
                                             : 384+h*48+(j-96);
                    b4[r] = qkv_b[row];
                }
                #pragma unroll
                for (int n=0;n<4;n++){
                    const int t = n*16 + lx;
                    union { ushort4 u; __hip_bfloat16 e[4]; } pk;
                    #pragma unroll
                    for (int r=0;r<4;r++)
                        pk.e[r] = __float2bfloat16(qa[mm][n][r] + b4[r]);
                    if (mt < 3)       *(ushort4*)&q_s[t*72 + j0]      = pk.u;
                    else if (mt < 6)  *(ushort4*)&k_s[t*72 + (j0-48)] = pk.u;
                    else {
                        #pragma unroll
                        for (int r=0;r<4;r++) v_s[(j0-96+r)*72 + t] = pk.e[r];
                    }
                }
            }
        }

        // ---------- scores: D[tq][tk], K=64 (zero-padded) ----------
        f32x4 sa[4][4];
        #pragma unroll
        for (int m=0;m<4;m++)
            #pragma unroll
            for (int n=0;n<4;n++) sa[m][n] = (f32x4){0.f,0.f,0.f,0.f};
        #pragma unroll
        for (int kc=0; kc<2; ++kc) {
            short8v bk[4];
            #pragma unroll
            for (int n=0;n<4;n++)
                bk[n] = *(const short8v*)&k_s[(n*16+lx)*72 + kc*32 + kg*8];
            #pragma unroll
            for (int m=0;m<4;m++) {
                short8v aq = *(const short8v*)&q_s[(m*16+lx)*72 + kc*32 + kg*8];
                #pragma unroll
                for (int n=0;n<4;n++)
                    sa[m][n] = __builtin_amdgcn_mfma_f32_16x16x32_bf16(
                                   aq, bk[n], sa[m][n], 0,0,0);
            }
        }

        // ---------- softmax (rows live in regs); p overlays q_s ----------
        #pragma unroll
        for (int m=0;m<4;m++) {
            #pragma unroll
            for (int r=0;r<4;r++) {
                const int trow = m*16 + kg*4 + r;
                float s[4];
                float mx = -1e30f;
                #pragma unroll
                for (int n=0;n<4;n++){
                    s[n] = sa[m][n][r]*scale + bias_full[trow][n*16+lx];
                    mx = fmaxf(mx, s[n]);
                }
                mx = fmaxf(mx, __shfl_xor(mx,1));
                mx = fmaxf(mx, __shfl_xor(mx,2));
                mx = fmaxf(mx, __shfl_xor(mx,4));
                mx = fmaxf(mx, __shfl_xor(mx,8));
                float l = 0.f;
                #pragma unroll
                for (int n=0;n<4;n++){ s[n] = __expf(s[n]-mx); l += s[n]; }
                l += __shfl_xor(l,1); l += __shfl_xor(l,2);
                l += __shfl_xor(l,4); l += __shfl_xor(l,8);
                const float inv = 1.f/l;
                #pragma unroll
                for (int n=0;n<4;n++)
                    q_s[trow*72 + n*16+lx] = __float2bfloat16(s[n]*inv);
            }
        }

        // ---------- PV: D[tq][d], A=p (q_s), B=v_s, K=64 ----------
        f32x4 oa[4][3];
        #pragma unroll
        for (int m=0;m<4;m++)
            #pragma unroll
            for (int n=0;n<3;n++) oa[m][n] = (f32x4){0.f,0.f,0.f,0.f};
        #pragma unroll
        for (int kc=0; kc<2; ++kc) {
            short8v bv[3];
            #pragma unroll
            for (int n=0;n<3;n++)
                bv[n] = *(const short8v*)&v_s[(n*16+lx)*72 + kc*32 + kg*8];
            #pragma unroll
            for (int m=0;m<4;m++) {
                short8v ap = *(const short8v*)&q_s[(m*16+lx)*72 + kc*32 + kg*8];
                #pragma unroll
                for (int n=0;n<3;n++)
                    oa[m][n] = __builtin_amdgcn_mfma_f32_16x16x32_bf16(
                                   ap, bv[n], oa[m][n], 0,0,0);
            }
        }
        // write o (overlays k_s) + zero pad cols 48..63
        #pragma unroll
        for (int m=0;m<4;m++)
            #pragma unroll
            for (int n=0;n<3;n++)
                #pragma unroll
                for (int r=0;r<4;r++)
                    k_s[(m*16+kg*4+r)*72 + n*16+lx] = __float2bfloat16(oa[m][n][r]);
        #pragma unroll
        for (int n=0;n<4;n++)
            *(ushort4*)&k_s[(n*16+lx)*72 + 48 + kg*4] = zz;

        // ---------- proj accumulate: D[oc][t], A=pw[h][oc][64], B=o ----------
        #pragma unroll
        for (int kc=0; kc<2; ++kc) {
            short8v bo[4];
            #pragma unroll
            for (int n=0;n<4;n++)
                bo[n] = *(const short8v*)&k_s[(n*16+lx)*72 + kc*32 + kg*8];
            #pragma unroll
            for (int m=0;m<12;m++) {
                short8v ap = *(const short8v*)
                    &pw[((size_t)(h*192 + m*16 + lx))*64 + kc*32 + kg*8];
                #pragma unroll
                for (int n=0;n<4;n++)
                    pacc[m][n] = __builtin_amdgcn_mfma_f32_16x16x32_bf16(
                                     ap, bo[n], pacc[m][n], 0,0,0);
            }
        }
    }

    // ---------- epilogue: out = x + attn + proj_b ----------
    const size_t base = (size_t)b*192*HWSZ + (size_t)(wi*8)*192 + wj*8;
    float* ob = out + base;
    const float* xr = x + base;
    #pragma unroll
    for (int m=0;m<12;m++) {
        #pragma unroll
        for (int r=0;r<4;r++) {
            const int oc = m*16 + kg*4 + r;
            const float pb = proj_b[oc];
            #pragma unroll
            for (int n=0;n<4;n++) {
                const int t = n*16 + lx;
                const size_t off = (size_t)oc*HWSZ + (t>>3)*192 + (t&7);
                ob[off] = xr[off] + pacc[m][n][r] + pb;
            }
        }
    }
}

// ---------------------------------------------------------------------------
// K2: 1x1 conv (C->2C) + GLU via MFMA (unchanged from R3)
// ---------------------------------------------------------------------------
__global__ __launch_bounds__(256)
void glu_mfma(const float* __restrict__ x1, const __hip_bfloat16* __restrict__ w1b,
              const float* __restrict__ w1_b, __hip_bfloat16* __restrict__ g)
{
    __shared__ __align__(16) __hip_bfloat16 Xs[64][200];

    const int tid  = threadIdx.x;
    const int bimg = blockIdx.x / 576;
    const int rem  = blockIdx.x - bimg*576;
    const int y    = rem / 3;
    const int x0   = (rem - y*3) * 64;

    const float* xb = x1 + (size_t)bimg*192*HWSZ + (size_t)y*192 + x0;
    for (int idx = tid; idx < 192*64; idx += 256){
        int c = idx >> 6, t = idx & 63;
        Xs[t][c] = __float2bfloat16(xb[(size_t)c*HWSZ + t]);
    }
    __syncthreads();

    const int lane = tid & 63;
    const int wv   = tid >> 6;
    const int lx   = lane & 15;
    const int kg   = lane >> 4;

    f32x4 gacc[6][4];
    #pragma unroll
    for (int m=0;m<6;m++)
        #pragma unroll
        for (int n=0;n<4;n++) gacc[m][n] = (f32x4){0.f,0.f,0.f,0.f};

    #pragma unroll 1
    for (int kc=0; kc<6; ++kc) {
        short8v bf[4];
        #pragma unroll
        for (int n=0;n<4;n++)
            bf[n] = *(const short8v*)&Xs[n*16+lx][kc*32+kg*8];
        #pragma unroll
        for (int mm=0; mm<6; ++mm) {
            const int m = (mm<3) ? (3*wv+mm) : (12 + 3*wv + mm-3);
            short8v af = *(const short8v*)&w1b[(size_t)(m*16+lx)*192 + kc*32 + kg*8];
            #pragma unroll
            for (int n=0;n<4;n++)
                gacc[mm][n] = __builtin_amdgcn_mfma_f32_16x16x32_bf16(
                                  af, bf[n], gacc[mm][n], 0,0,0);
        }
    }
    __syncthreads();

    #pragma unroll
    for (int mm=0; mm<3; ++mm) {
        #pragma unroll
        for (int r=0;r<4;r++) {
            const int oc = (3*wv+mm)*16 + kg*4 + r;
            const float ba = w1_b[oc], bb = w1_b[oc+192];
            #pragma unroll
            for (int n=0;n<4;n++) {
                const float a  = gacc[mm][n][r]   + ba;
                const float bv = gacc[mm+3][n][r] + bb;
                Xs[n*16+lx][oc] = __float2bfloat16(a * (1.f/(1.f+__expf(-bv))));
            }
        }
    }
    __syncthreads();

    __hip_bfloat16* gb = g + ((size_t)bimg*HWSZ + (size_t)y*192 + x0)*192;
    for (int idx = tid; idx < 64*24; idx += 256){
        int p = idx / 24, c8 = (idx - p*24)*8;
        *(uint4*)&gb[(size_t)p*192 + c8] = *(const uint4*)&Xs[p][c8];
    }
}

// ---------------------------------------------------------------------------
// K3: 3x3 conv via 9-tap shifted MFMA GEMM (unchanged from R2)
// ---------------------------------------------------------------------------
#define KC 32
__global__ __launch_bounds__(256)
void conv_mfma(const __hip_bfloat16* __restrict__ g,
               const __hip_bfloat16* __restrict__ wg,
               const float* __restrict__ w2_b, float* __restrict__ out)
{
    __shared__ __align__(16) __hip_bfloat16 gt[10*18*32];
    __shared__ __align__(16) __hip_bfloat16 wt[9*96*32];

    int bid = blockIdx.x;
    const int tX = bid % 12; bid /= 12;
    const int tY = bid % 24; bid /= 24;
    const int ob = bid & 1;  bid >>= 1;
    const int bimg = bid;
    const int tx0 = tX*16, ty0 = tY*8, oc0 = ob*96;

    const int tid  = threadIdx.x;
    const int lane = tid & 63;
    const int wv   = tid >> 6;
    const int wm   = wv >> 1;
    const int wn   = wv & 1;
    const int lx   = lane & 15;
    const int kg   = lane >> 4;

    f32x4 acc[3][4];
    #pragma unroll
    for (int m=0;m<3;m++)
        #pragma unroll
        for (int n=0;n<4;n++) acc[m][n] = (f32x4){0.f,0.f,0.f,0.f};

    const size_t gbase = (size_t)bimg*HWSZ;

    for (int c0 = 0; c0 < 192; c0 += KC) {
        for (int idx = tid; idx < 720; idx += 256) {
            int px = idx >> 2, part = idx & 3;
            int iy = px / 18, ix = px - iy*18;
            int gy = min(max(ty0 + iy - 1, 0), 191);
            int gx = min(max(tx0 + ix - 1, 0), 191);
            *(uint4*)&gt[(iy*18+ix)*32 + part*8] =
                *(const uint4*)&g[(gbase + (size_t)gy*192 + gx)*192 + c0 + part*8];
        }
        for (int idx = tid; idx < 3456; idx += 256) {
            int tap = idx / 384; int rr = idx - tap*384;
            int ocl = rr >> 2, part = rr & 3;
            *(uint4*)&wt[(tap*96+ocl)*32 + part*8] =
                *(const uint4*)&wg[(size_t)tap*36864 + (size_t)(oc0+ocl)*192 + c0 + part*8];
        }
        __syncthreads();

        #pragma unroll
        for (int ky=0; ky<3; ++ky) {
            #pragma unroll
            for (int kx=0; kx<3; ++kx) {
                const int tap = ky*3+kx;
                short8v a[3], b[4];
                #pragma unroll
                for (int m=0;m<3;m++)
                    a[m] = *(const short8v*)&wt[(tap*96 + wm*48 + m*16 + lx)*32 + kg*8];
                #pragma unroll
                for (int n=0;n<4;n++)
                    b[n] = *(const short8v*)&gt[((wn*4 + n + ky)*18 + lx + kx)*32 + kg*8];
                #pragma unroll
                for (int m=0;m<3;m++)
                    #pragma unroll
                    for (int n=0;n<4;n++)
                        acc[m][n] = __builtin_amdgcn_mfma_f32_16x16x32_bf16(
                                        a[m], b[n], acc[m][n], 0, 0, 0);
            }
        }
        __syncthreads();
    }

    #pragma unroll
    for (int m=0;m<3;m++) {
        const int ocb_ = oc0 + wm*48 + m*16 + kg*4;
        #pragma unroll
        for (int n=0;n<4;n++) {
            const int y = ty0 + wn*4 + n;
            const int x = tx0 + lx;
            #pragma unroll
            for (int r=0;r<4;r++) {
                const int oc = ocb_ + r;
                const size_t o = ((size_t)(bimg*192+oc))*HWSZ + (size_t)y*192 + x;
                float v = acc[m][n][r] + w2_b[oc];
                v = (v >= 0.f) ? v : 0.2f*v;
                out[o] += v;
            }
        }
    }
}

// ---------------------------------------------------------------------------
extern "C" void kernel_launch(void* const* d_in, const int* in_sizes, int n_in,
                              void* d_out, int out_size, void* d_ws, size_t ws_size,
                              hipStream_t stream)
{
    const float* x        = (const float*)d_in[0];
    const float* qkv_w    = (const float*)d_in[1];
    const float* qkv_b    = (const float*)d_in[2];
    const float* proj_w   = (const float*)d_in[3];
    const float* proj_b   = (const float*)d_in[4];
    const float* bias_tab = (const float*)d_in[5];
    const float* w1_w     = (const float*)d_in[6];
    const float* w1_b     = (const float*)d_in[7];
    const float* w2_w     = (const float*)d_in[8];
    const float* w2_b     = (const float*)d_in[9];
    float* out = (float*)d_out;

    // buffer0 (113.25 MB): xbf during attn, then reused as g for glu/conv
    __hip_bfloat16* buf0 = (__hip_bfloat16*)d_ws;
    char* wp = (char*)d_ws + (size_t)8*HWSZ*192*2;
    __hip_bfloat16* wg  = (__hip_bfloat16*)wp;
    __hip_bfloat16* wqp = (__hip_bfloat16*)(wp + (size_t)WG_N*2);
    __hip_bfloat16* pwp = (__hip_bfloat16*)(wp + (size_t)(WG_N+WQ_N)*2);
    __hip_bfloat16* w1b = (__hip_bfloat16*)(wp + (size_t)(WG_N+WQ_N+PW_N)*2);

    prep_weights<<<2208, 256, 0, stream>>>(w2_w, qkv_w, proj_w, w1_w, wg, wqp, pwp, w1b);
    to_bf16_pm  <<<4608, 256, 0, stream>>>(x, buf0);
    attn_wave   <<<1152, 256, 0, stream>>>(buf0, x, wqp, qkv_b, pwp, proj_b, bias_tab, out);
    glu_mfma    <<<4608, 256, 0, stream>>>(out, w1b, w1_b, buf0);
    conv_mfma   <<<4608, 256, 0, stream>>>(buf0, wg, w2_b, out);
}